// Round 1
// baseline (1054.953 us; speedup 1.0000x reference)
//
#include <hip/hip_runtime.h>
#include <math.h>

typedef unsigned short u16;
typedef __attribute__((ext_vector_type(4))) float f32x4;
typedef __attribute__((ext_vector_type(8))) __bf16 bf16x8;

#define GLDS16(g, l) __builtin_amdgcn_global_load_lds(                        \
    (const __attribute__((address_space(1))) void*)(g),                       \
    (__attribute__((address_space(3))) void*)(l), 16, 0, 0)

__device__ __forceinline__ u16 f2b(float x){
  unsigned u = __float_as_uint(x);
  u = (u + 0x7FFFu + ((u >> 16) & 1u)) >> 16;
  return (u16)u;
}
__device__ __forceinline__ float b2f(u16 u){ return __uint_as_float(((unsigned)u) << 16); }
__device__ __forceinline__ f32x4 zero4(){ f32x4 v; v[0]=0.f; v[1]=0.f; v[2]=0.f; v[3]=0.f; return v; }
__device__ __forceinline__ float sigm(float x){ return 1.f/(1.f+expf(-x)); }

// ---------------- elementwise fp32 -> bf16 ----------------
__global__ void k_f2b(const float* __restrict__ s, u16* __restrict__ d, size_t n){
  size_t i = ((size_t)blockIdx.x*blockDim.x + threadIdx.x)*4;
  size_t stride = (size_t)gridDim.x*blockDim.x*4;
  for (; i < n; i += stride){
    float4 v = *(const float4*)(s + i);
    u16 o0 = f2b(v.x), o1 = f2b(v.y), o2 = f2b(v.z), o3 = f2b(v.w);
    d[i] = o0; d[i+1] = o1; d[i+2] = o2; d[i+3] = o3;
  }
}

__global__ void k_bias4(const float* __restrict__ bih, const float* __restrict__ bhh, float* __restrict__ b4){
  int i = blockIdx.x*256 + threadIdx.x;
  if (i < 4096) b4[i] = bih[i] + bhh[i];
}

__global__ void k_init(const float* __restrict__ h, const float* __restrict__ c,
                       float* __restrict__ hc, float* __restrict__ cc, u16* __restrict__ hb){
  int i = blockIdx.x*256 + threadIdx.x;
  if (i < 32768){ hc[i] = h[i]; cc[i] = c[i]; hb[i] = f2b(h[i]); }
}

// gather embedding rows -> bf16 e_seq [2048][512]
__global__ void k_gather(const int* __restrict__ x, const float* __restrict__ emb, u16* __restrict__ e){
  int row = blockIdx.x;               // t*32+b
  int xi = x[row];
  const float* er = emb + (size_t)xi*512;
  u16* dr = e + (size_t)row*512;
  for (int k = threadIdx.x; k < 512; k += 256) dr[k] = f2b(er[k]);
}

// ---------------- generic C = A*B^T (+bias, epi) bf16 MFMA GEMM -----------
// A [M][K] bf16 row-major, B [N][K] bf16 row-major. 128x128 tile, BK=32.
// EPI: 0 = bf16 store (+bias), 1 = bf16 store tanh(+bias), 2 = fp32 store (+bias)
template<int EPI>
__global__ __launch_bounds__(256) void gemm_bt(
    const u16* __restrict__ A, const u16* __restrict__ B,
    const float* __restrict__ bias, void* __restrict__ Cv,
    int K, int ldc, int ntn)
{
  __shared__ u16 sA[128*32];
  __shared__ u16 sB[128*32];
  int bid = blockIdx.x;
  int mt = bid / ntn, nt = bid % ntn;
  int m0 = mt*128, n0 = nt*128;
  int tid = threadIdx.x, lane = tid & 63, wid = tid >> 6;
  int q = lane & 3, rr = lane >> 2;
  int c0 = wid*2, c1 = wid*2+1;
  const u16* gA0 = A + (size_t)(m0 + c0*16 + rr)*K + q*8;
  const u16* gA1 = A + (size_t)(m0 + c1*16 + rr)*K + q*8;
  const u16* gB0 = B + (size_t)(n0 + c0*16 + rr)*K + q*8;
  const u16* gB1 = B + (size_t)(n0 + c1*16 + rr)*K + q*8;
  f32x4 acc[4][4];
#pragma unroll
  for (int m=0;m<4;++m)
#pragma unroll
    for (int n=0;n<4;++n) acc[m][n] = zero4();
  int wr = wid >> 1, wc = wid & 1;
  int lr = lane & 15, ks = lane >> 4;
  int aoff = (wr*64 + lr)*32 + ks*8;
  int boff = (wc*64 + lr)*32 + ks*8;
  for (int k0 = 0; k0 < K; k0 += 32){
    GLDS16(gA0 + k0, sA + c0*512);
    GLDS16(gA1 + k0, sA + c1*512);
    GLDS16(gB0 + k0, sB + c0*512);
    GLDS16(gB1 + k0, sB + c1*512);
    __syncthreads();
    bf16x8 af[4], bfr[4];
#pragma unroll
    for (int m=0;m<4;++m) af[m] = *(const bf16x8*)&sA[aoff + m*512];
#pragma unroll
    for (int n=0;n<4;++n) bfr[n] = *(const bf16x8*)&sB[boff + n*512];
#pragma unroll
    for (int m=0;m<4;++m)
#pragma unroll
      for (int n=0;n<4;++n)
        acc[m][n] = __builtin_amdgcn_mfma_f32_16x16x32_bf16(af[m], bfr[n], acc[m][n], 0, 0, 0);
    __syncthreads();
  }
#pragma unroll
  for (int m=0;m<4;++m){
    int crow = m0 + wr*64 + m*16 + ks*4;
#pragma unroll
    for (int n=0;n<4;++n){
      int ccol = n0 + wc*64 + n*16 + lr;
      float bv = bias ? bias[ccol] : 0.f;
#pragma unroll
      for (int r=0;r<4;++r){
        float v = acc[m][n][r] + bv;
        if (EPI == 1) v = tanhf(v);
        if (EPI == 2) ((float*)Cv)[(size_t)(crow + r)*ldc + ccol] = v;
        else          ((u16*)Cv)[(size_t)(crow + r)*ldc + ccol] = f2b(v);
      }
    }
  }
}

// ---------------- one LSTM step: gates GEMM + pointwise -------------------
// grid 256 WGs x 64 threads. WG n owns h-cols [n*4, n*4+4) => 16 gate cols
// {g*1024 + n*4 + d}. A = h_{t-1} bf16 [32][1024], B = W_hh slice.
// LDS staged in two K-halves of 512 with XOR swizzle (rule #21: swizzle the
// global source, read with the same XOR; global_load_lds dest stays linear).
__global__ __launch_bounds__(64) void k_step(
    const u16* __restrict__ pre,   // [2048][4096] bf16 (e@W_ih^T + biases)
    const u16* __restrict__ Whh,   // [4096][1024] bf16
    const u16* __restrict__ hin,   // [32][1024] bf16
    u16* __restrict__ hout,        // [32][1024] bf16
    float* __restrict__ hc, float* __restrict__ cc,
    u16* __restrict__ concat,      // [2048][2048] bf16; cols 0..1023 <- h_t
    int t)
{
  __shared__ u16 sA[32*512];   // 32 rows x 512 k (swizzled within row)
  __shared__ u16 sB[16*512];
  int n = blockIdx.x;
  int lane = threadIdx.x;
  f32x4 acc0 = zero4(), acc1 = zero4();
  int lr = lane & 15, ks = lane >> 4;
  for (int half = 0; half < 2; ++half){
    int kbase = half*512;
    // stage A: one wave-pass per row (row = 1KB). source k-offset pre-swizzled.
#pragma unroll 4
    for (int r = 0; r < 32; ++r){
      int koff = (lane*8) ^ ((r & 7) << 3);     // ushort units, 16B-granular XOR
      GLDS16(hin + (size_t)r*1024 + kbase + koff, sA + r*512);
    }
#pragma unroll 4
    for (int jj = 0; jj < 16; ++jj){
      int koff = (lane*8) ^ ((jj & 7) << 3);
      GLDS16(Whh + (size_t)((jj>>2)*1024 + n*4 + (jj&3))*1024 + kbase + koff, sB + jj*512);
    }
    __syncthreads();
#pragma unroll 8
    for (int kk = 0; kk < 512; kk += 32){
      int ka0 = (kk + ks*8) ^ ((lr & 7) << 3);
      bf16x8 a0 = *(const bf16x8*)&sA[lr*512 + ka0];
      bf16x8 a1 = *(const bf16x8*)&sA[(16+lr)*512 + ka0];
      bf16x8 bb = *(const bf16x8*)&sB[lr*512 + ka0];
      acc0 = __builtin_amdgcn_mfma_f32_16x16x32_bf16(a0, bb, acc0, 0, 0, 0);
      acc1 = __builtin_amdgcn_mfma_f32_16x16x32_bf16(a1, bb, acc1, 0, 0, 0);
    }
    __syncthreads();
  }
  // gates -> LDS (reuse sA), grouped per (b, d)
  float* gbuf = (float*)sA;   // [32][16]
#pragma unroll
  for (int r = 0; r < 4; ++r){
    int b0 = ks*4 + r;
    int gv_col = (lr >> 2)*1024 + n*4 + (lr & 3);
    gbuf[(b0)*16 + lr]      = acc0[r] + b2f(pre[(size_t)(t*32 + b0)*4096 + gv_col]);
    gbuf[(16+b0)*16 + lr]   = acc1[r] + b2f(pre[(size_t)(t*32 + 16 + b0)*4096 + gv_col]);
  }
  __syncthreads();
#pragma unroll
  for (int rep = 0; rep < 2; ++rep){
    int idx = lane + rep*64;        // 0..127 = 32 b x 4 d
    int b = idx >> 2, d = idx & 3;
    int hcol = n*4 + d;
    float iv = gbuf[b*16 + d],     fv = gbuf[b*16 + 4 + d];
    float gv = gbuf[b*16 + 8 + d], ov = gbuf[b*16 + 12 + d];
    float cp = cc[b*1024 + hcol];
    float cn = sigm(fv)*cp + sigm(iv)*tanhf(gv);
    float hn = sigm(ov)*tanhf(cn);
    cc[b*1024 + hcol] = cn;
    hc[b*1024 + hcol] = hn;
    u16 hb = f2b(hn);
    hout[b*1024 + hcol] = hb;
    concat[((size_t)t*32 + b)*2048 + hcol] = hb;
  }
}

// ---------------- attention for one (t,b): scores/softmax/weighted --------
__global__ __launch_bounds__(256) void k_attn(const u16* __restrict__ ctx,   // [32][64][1024] bf16
                                              u16* __restrict__ concat){     // [2048][2048]
  int row = blockIdx.x;           // t*32+b
  int b = row & 31;
  int tid = threadIdx.x, lane = tid & 63, w = tid >> 6;
  __shared__ float sc[64];
  __shared__ float wacc[4][1024];
  const u16* hr = concat + (size_t)row*2048;
  float hv[16];
#pragma unroll
  for (int i = 0; i < 16; ++i) hv[i] = b2f(hr[lane + 64*i]);
  const u16* cb = ctx + (size_t)b*64*1024;
  for (int sl = 0; sl < 16; ++sl){
    int s = w*16 + sl;
    const u16* cr = cb + (size_t)s*1024;
    float a = 0.f;
#pragma unroll
    for (int i = 0; i < 16; ++i) a += b2f(cr[lane + 64*i]) * hv[i];
#pragma unroll
    for (int off = 32; off; off >>= 1) a += __shfl_xor(a, off);
    if (lane == 0) sc[s] = a;
  }
  __syncthreads();
  if (w == 0){
    float x = sc[lane];
    float mx = x;
#pragma unroll
    for (int off = 32; off; off >>= 1) mx = fmaxf(mx, __shfl_xor(mx, off));
    float p = expf(x - mx);
    float sum = p;
#pragma unroll
    for (int off = 32; off; off >>= 1) sum += __shfl_xor(sum, off);
    sc[lane] = p / sum;
  }
  __syncthreads();
  float acc2[16];
#pragma unroll
  for (int i = 0; i < 16; ++i) acc2[i] = 0.f;
  for (int sl = 0; sl < 16; ++sl){
    int s = w*16 + sl;
    float a = sc[s];
    const u16* cr = cb + (size_t)s*1024;
#pragma unroll
    for (int i = 0; i < 16; ++i) acc2[i] += a * b2f(cr[lane + 64*i]);
  }
#pragma unroll
  for (int i = 0; i < 16; ++i) wacc[w][lane + 64*i] = acc2[i];
  __syncthreads();
  int h0 = tid*4;
#pragma unroll
  for (int r = 0; r < 4; ++r){
    int hh = h0 + r;
    float sv = wacc[0][hh] + wacc[1][hh] + wacc[2][hh] + wacc[3][hh];
    concat[(size_t)row*2048 + 1024 + hh] = f2b(sv);
  }
}

// ---------------- logsumexp per row of logits ----------------
__global__ __launch_bounds__(256) void k_lse(const float* __restrict__ logits, float* __restrict__ lse){
  int row = blockIdx.x;
  const float* p = logits + (size_t)row*32000;
  int tid = threadIdx.x;
  float m = -3.4e38f, s = 0.f;
  for (int v = tid; v < 32000; v += 256){
    float x = p[v];
    if (x > m){ s = s*expf(m - x) + 1.f; m = x; }
    else s += expf(x - m);
  }
#pragma unroll
  for (int off = 32; off; off >>= 1){
    float m2 = __shfl_xor(m, off), s2 = __shfl_xor(s, off);
    float M = fmaxf(m, m2);
    s = s*expf(m - M) + s2*expf(m2 - M); m = M;
  }
  __shared__ float sm[4], ss[4];
  if ((tid & 63) == 0){ sm[tid>>6] = m; ss[tid>>6] = s; }
  __syncthreads();
  if (tid == 0){
#pragma unroll
    for (int w2 = 1; w2 < 4; ++w2){
      float M = fmaxf(m, sm[w2]);
      s = s*expf(m - M) + ss[w2]*expf(sm[w2] - M); m = M;
    }
    lse[row] = m + logf(s);
  }
}

__global__ void k_sub(float* __restrict__ out, const float* __restrict__ lse){
  size_t i = (size_t)blockIdx.x*256 + threadIdx.x;
  size_t stride = (size_t)gridDim.x*256;
  for (; i < 16384000UL; i += stride){           // float4 count
    float4 v = ((float4*)out)[i];
    float l = lse[i / 8000];                      // 8000 float4 per row
    v.x -= l; v.y -= l; v.z -= l; v.w -= l;
    ((float4*)out)[i] = v;
  }
}

__global__ void k_tail(const float* __restrict__ hc, const float* __restrict__ cc, float* __restrict__ o){
  int i = blockIdx.x*256 + threadIdx.x;
  if (i < 32768){ o[i] = hc[i]; o[32768 + i] = cc[i]; }
}

// --------------------------------------------------------------------------
extern "C" void kernel_launch(void* const* d_in, const int* in_sizes, int n_in,
                              void* d_out, int out_size, void* d_ws, size_t ws_size,
                              hipStream_t stream) {
  const int*   x_seq   = (const int*)  d_in[0];
  const float* h_in    = (const float*)d_in[1];
  const float* c_in    = (const float*)d_in[2];
  const float* context = (const float*)d_in[3];
  const float* emb     = (const float*)d_in[4];
  const float* W_ih    = (const float*)d_in[5];
  const float* W_hh    = (const float*)d_in[6];
  const float* b_ih    = (const float*)d_in[7];
  const float* b_hh    = (const float*)d_in[8];
  const float* W_a     = (const float*)d_in[9];
  const float* b_a     = (const float*)d_in[10];
  const float* W_o     = (const float*)d_in[11];
  const float* b_o     = (const float*)d_in[12];
  float* out = (float*)d_out;

  char* ws = (char*)d_ws;
  size_t off = 0;
  auto alloc = [&](size_t bytes)->void*{ void* p = ws + off; off += (bytes + 255) & ~(size_t)255; return p; };
  u16* W_ih_b = (u16*)alloc((size_t)4096*512*2);
  u16* W_hh_b = (u16*)alloc((size_t)4096*1024*2);
  u16* W_a_b  = (u16*)alloc((size_t)1024*2048*2);
  u16* W_o_b  = (u16*)alloc((size_t)32000*1024*2);
  u16* ctx_b  = (u16*)alloc((size_t)32*64*1024*2);
  float* bias4 = (float*)alloc(4096*4);
  u16* e_seq  = (u16*)alloc((size_t)2048*512*2);
  u16* pre    = (u16*)alloc((size_t)2048*4096*2);
  u16* concat = (u16*)alloc((size_t)2048*2048*2);
  u16* a_seq  = (u16*)alloc((size_t)2048*1024*2);
  float* h_cur = (float*)alloc(32768*4);
  float* c_cur = (float*)alloc(32768*4);
  u16* hb0    = (u16*)alloc(32768*2);
  u16* hb1    = (u16*)alloc(32768*2);
  float* lse  = (float*)alloc(2048*4);

  auto g4 = [](size_t n)->int{ size_t g = (n/4 + 255)/256; return (int)(g > 4096 ? 4096 : g); };

  // weight/context conversions to bf16
  k_f2b<<<g4(2097152), 256, 0, stream>>>(W_ih, W_ih_b, 2097152);
  k_f2b<<<g4(4194304), 256, 0, stream>>>(W_hh, W_hh_b, 4194304);
  k_f2b<<<g4(2097152), 256, 0, stream>>>(W_a,  W_a_b,  2097152);
  k_f2b<<<g4(32768000),256, 0, stream>>>(W_o,  W_o_b,  32768000);
  k_f2b<<<g4(2097152), 256, 0, stream>>>(context, ctx_b, 2097152);
  k_bias4<<<16, 256, 0, stream>>>(b_ih, b_hh, bias4);
  k_init<<<128, 256, 0, stream>>>(h_in, c_in, h_cur, c_cur, hb0);
  k_gather<<<2048, 256, 0, stream>>>(x_seq, emb, e_seq);

  // pre_ih = e @ W_ih^T + (b_ih + b_hh)   [2048 x 4096] bf16
  gemm_bt<0><<<16*32, 256, 0, stream>>>(e_seq, W_ih_b, bias4, pre, 512, 4096, 32);

  // recurrence
  for (int t = 0; t < 64; ++t){
    u16* hi = (t & 1) ? hb1 : hb0;
    u16* ho = (t & 1) ? hb0 : hb1;
    k_step<<<256, 64, 0, stream>>>(pre, W_hh_b, hi, ho, h_cur, c_cur, concat, t);
  }

  // attention (all t,b in parallel) -> concat[:,1024:2048]
  k_attn<<<2048, 256, 0, stream>>>(ctx_b, concat);

  // a = tanh(concat @ W_a^T + b_a)  [2048 x 1024] bf16
  gemm_bt<1><<<16*8, 256, 0, stream>>>(concat, W_a_b, b_a, a_seq, 2048, 1024, 8);

  // logits = a @ W_o^T + b_o  -> d_out fp32 [2048 x 32000]
  gemm_bt<2><<<16*250, 256, 0, stream>>>(a_seq, W_o_b, b_o, out, 1024, 32000, 250);

  // log_softmax in place
  k_lse<<<2048, 256, 0, stream>>>(out, lse);
  k_sub<<<8192, 256, 0, stream>>>(out, lse);

  // final h, c
  k_tail<<<128, 256, 0, stream>>>(h_cur, c_cur, out + 65536000);
}